// Round 1
// baseline (1269.610 us; speedup 1.0000x reference)
//
#include <hip/hip_runtime.h>
#include <cstdint>
#include <cstddef>

#define NEXP 7
#define EMBED_DIM 16
#define FOURH 1024
#define TWOH 512
#define HID 256
#define S_MAX 16641
#define D_IN (S_MAX + EMBED_DIM)
#define BATCH 1024
#define KCHUNK 512
#define MT 32

// sizes per expert: (2^(o+1)+1)^2
__constant__ int d_SIZES[NEXP] = {9, 25, 81, 289, 1089, 4225, 16641};
// ceil(size/KCHUNK) = {1,1,1,1,3,9,33}; prefix sums:
__constant__ int d_KCOFF[NEXP + 1] = {0, 1, 2, 3, 4, 7, 16, 49};

__device__ __forceinline__ float lrelu(float x) { return x > 0.f ? x : 0.2f * x; }

// ---------------- bucket samples by expert ----------------
__global__ __launch_bounds__(1024) void bucket_kernel(
    const int* __restrict__ orders, int* __restrict__ counts,
    int* __restrict__ bases, int* __restrict__ list) {
  __shared__ int c[NEXP], p[NEXP];
  int t = threadIdx.x;
  if (t < NEXP) c[t] = 0;
  __syncthreads();
  int o = orders[t];
  atomicAdd(&c[o], 1);
  __syncthreads();
  if (t == 0) {
    int s = 0;
    for (int i = 0; i < NEXP; ++i) { p[i] = s; s += c[i]; }
  }
  __syncthreads();
  if (t < NEXP) { counts[t] = c[t]; bases[t] = p[t]; }
  __syncthreads();
  int pos = atomicAdd(&p[o], 1);
  list[pos] = t;
}

// ---------------- per-expert embed+bias init vector (7 x 1024) ----------------
__global__ __launch_bounds__(1024) void hinit_kernel(
    const float* __restrict__ embed, const float* __restrict__ W_in,
    const float* __restrict__ b_in, float* __restrict__ hinit) {
  int o = blockIdx.x, j = threadIdx.x;
  float a = b_in[o * FOURH + j];
  const float* wr = W_in + (size_t)o * D_IN * FOURH + (size_t)S_MAX * FOURH + j;
#pragma unroll
  for (int e = 0; e < EMBED_DIM; ++e)
    a = fmaf(embed[o * EMBED_DIM + e], wr[(size_t)e * FOURH], a);
  hinit[o * FOURH + j] = a;
}

// ---------------- grouped layer-in GEMM, K-split, atomic partials ----------------
__global__ __launch_bounds__(256) void layerin_kernel(
    const float* __restrict__ mazes, const float* __restrict__ W_in,
    const int* __restrict__ counts, const int* __restrict__ bases,
    const int* __restrict__ list, const float* __restrict__ hinit,
    float* __restrict__ h) {
  int bx = blockIdx.x;
  int o = 0;
#pragma unroll
  for (int t = 1; t < NEXP; ++t)
    if (bx >= d_KCOFF[t]) o = t;
  int kc = bx - d_KCOFF[o];
  int jt = blockIdx.y, mt = blockIdx.z;
  int n = counts[o];
  int m0 = mt * MT;
  if (m0 >= n) return;

  __shared__ int sid[MT];
  int tid = threadIdx.x;
  if (tid < MT) {
    int r = m0 + tid;
    sid[tid] = list[bases[o] + (r < n ? r : 0)];
  }
  __syncthreads();

  int j = jt * 256 + tid;
  int so = d_SIZES[o];
  int klo = kc * KCHUNK;
  int khi = min(so, klo + KCHUNK);

  // wave-uniform maze row pointers (scalar-pipe candidates)
  const float* mp[MT];
#pragma unroll
  for (int i = 0; i < MT; ++i) {
    int b = __builtin_amdgcn_readfirstlane(sid[i]);
    mp[i] = mazes + (size_t)b * S_MAX;
  }

  const float* wp = W_in + (size_t)o * D_IN * FOURH + (size_t)klo * FOURH + j;
  float acc[MT];
#pragma unroll
  for (int i = 0; i < MT; ++i) acc[i] = 0.f;

  int k = klo;
  for (; k + 4 <= khi; k += 4) {
    float w0 = wp[0];
    float w1 = wp[FOURH];
    float w2 = wp[2 * FOURH];
    float w3 = wp[3 * FOURH];
    wp += 4 * FOURH;
#pragma unroll
    for (int i = 0; i < MT; ++i) {
      const float* r = mp[i] + k;
      acc[i] = fmaf(r[0], w0, fmaf(r[1], w1, fmaf(r[2], w2, fmaf(r[3], w3, acc[i]))));
    }
  }
  for (; k < khi; ++k) {
    float w0 = *wp;
    wp += FOURH;
#pragma unroll
    for (int i = 0; i < MT; ++i) acc[i] = fmaf(mp[i][k], w0, acc[i]);
  }

  float hv = (kc == 0) ? hinit[o * FOURH + j] : 0.f;
#pragma unroll
  for (int i = 0; i < MT; ++i) {
    if (m0 + i < n) atomicAdd(&h[(size_t)sid[i] * FOURH + j], acc[i] + hv);
  }
}

// ---------------- in-place leaky relu on h ----------------
__global__ __launch_bounds__(256) void lrelu_kernel(float* __restrict__ h) {
  int idx = blockIdx.x * blockDim.x + threadIdx.x;
  float4* p = (float4*)h;
  float4 v = p[idx];
  v.x = lrelu(v.x);
  v.y = lrelu(v.y);
  v.z = lrelu(v.z);
  v.w = lrelu(v.w);
  p[idx] = v;
}

// ---------------- layer1: [1024,1024] @ [1024,512] ----------------
__global__ __launch_bounds__(256) void layer1_kernel(
    const float* __restrict__ h, const float* __restrict__ W1,
    const float* __restrict__ b1, float* __restrict__ z1) {
  int j = blockIdx.x * 256 + threadIdx.x;
  int m0 = blockIdx.y * 8;
  const float* hr = h + (size_t)m0 * FOURH;
  float acc[8];
#pragma unroll
  for (int i = 0; i < 8; ++i) acc[i] = 0.f;
  const float* wp = W1 + j;
#pragma unroll 4
  for (int k = 0; k < FOURH; ++k) {
    float w = wp[(size_t)k * TWOH];
#pragma unroll
    for (int i = 0; i < 8; ++i) acc[i] = fmaf(hr[(size_t)i * FOURH + k], w, acc[i]);
  }
  float bb = b1[j];
#pragma unroll
  for (int i = 0; i < 8; ++i)
    z1[(size_t)(m0 + i) * TWOH + j] = lrelu(acc[i] + bb);
}

// ---------------- layer2: [1024,512] @ [512,256] ----------------
__global__ __launch_bounds__(256) void layer2_kernel(
    const float* __restrict__ z1, const float* __restrict__ W2,
    const float* __restrict__ b2, float* __restrict__ z2) {
  int j = threadIdx.x;
  int m0 = blockIdx.y * 8;
  const float* zr = z1 + (size_t)m0 * TWOH;
  float acc[8];
#pragma unroll
  for (int i = 0; i < 8; ++i) acc[i] = 0.f;
  const float* wp = W2 + j;
#pragma unroll 4
  for (int k = 0; k < TWOH; ++k) {
    float w = wp[(size_t)k * HID];
#pragma unroll
    for (int i = 0; i < 8; ++i) acc[i] = fmaf(zr[(size_t)i * TWOH + k], w, acc[i]);
  }
  float bb = b2[j];
#pragma unroll
  for (int i = 0; i < 8; ++i)
    z2[(size_t)(m0 + i) * HID + j] = lrelu(acc[i] + bb);
}

// ---------------- layer3: [1024,256] @ [256,1] + sigmoid ----------------
__global__ __launch_bounds__(256) void layer3_kernel(
    const float* __restrict__ z2, const float* __restrict__ W3,
    const float* __restrict__ b3, float* __restrict__ out) {
  int wave = threadIdx.x >> 6, lane = threadIdx.x & 63;
  int b = blockIdx.x * 4 + wave;
  float4 v = *(const float4*)&z2[(size_t)b * HID + lane * 4];
  float4 w = *(const float4*)&W3[lane * 4];
  float d = v.x * w.x + v.y * w.y + v.z * w.z + v.w * w.w;
#pragma unroll
  for (int off = 32; off; off >>= 1) d += __shfl_down(d, off);
  if (lane == 0) out[b] = 1.f / (1.f + expf(-(d + b3[0])));
}

extern "C" void kernel_launch(void* const* d_in, const int* in_sizes, int n_in,
                              void* d_out, int out_size, void* d_ws, size_t ws_size,
                              hipStream_t stream) {
  const float* mazes = (const float*)d_in[0];
  const int* orders = (const int*)d_in[1];
  const float* embed = (const float*)d_in[2];
  const float* W_in = (const float*)d_in[3];
  const float* b_in = (const float*)d_in[4];
  const float* W1 = (const float*)d_in[5];
  const float* b1 = (const float*)d_in[6];
  const float* W2 = (const float*)d_in[7];
  const float* b2 = (const float*)d_in[8];
  const float* W3 = (const float*)d_in[9];
  const float* b3 = (const float*)d_in[10];
  float* out = (float*)d_out;

  char* ws = (char*)d_ws;
  int* counts = (int*)ws;       // 7 ints
  int* bases = counts + 8;      // 7 ints
  int* list = counts + 16;      // 1024 ints
  float* hinit = (float*)(ws + 64 * 1024);                     // 7*1024 f32
  float* h = (float*)(ws + 128 * 1024);                        // 1024*1024 f32 (4 MB)
  float* z1 = (float*)(ws + 128 * 1024 + 4 * 1024 * 1024);     // 1024*512 f32 (2 MB)
  float* z2 = h;  // overlay: h is dead after layer1 consumes it

  bucket_kernel<<<1, 1024, 0, stream>>>(orders, counts, bases, list);
  hinit_kernel<<<NEXP, 1024, 0, stream>>>(embed, W_in, b_in, hinit);
  hipMemsetAsync(h, 0, (size_t)BATCH * FOURH * sizeof(float), stream);
  layerin_kernel<<<dim3(49, 4, 32), 256, 0, stream>>>(mazes, W_in, counts, bases, list, hinit, h);
  lrelu_kernel<<<1024, 256, 0, stream>>>(h);
  layer1_kernel<<<dim3(2, 128), 256, 0, stream>>>(h, W1, b1, z1);
  layer2_kernel<<<dim3(1, 128), 256, 0, stream>>>(z1, W2, b2, z2);
  layer3_kernel<<<256, 256, 0, stream>>>(z2, W3, b3, out);
}

// Round 2
// 934.263 us; speedup vs baseline: 1.3589x; 1.3589x over previous
//
#include <hip/hip_runtime.h>
#include <cstdint>
#include <cstddef>

#define NEXP 7
#define EMBED_DIM 16
#define FOURH 1024
#define TWOH 512
#define HID 256
#define S_MAX 16641
#define D_IN (S_MAX + EMBED_DIM)
#define BATCH 1024
#define KCHUNK 512
#define KT 128
#define MT 32

// sizes per expert: (2^(o+1)+1)^2
__constant__ int d_SIZES[NEXP] = {9, 25, 81, 289, 1089, 4225, 16641};
// ceil(size/KCHUNK) = {1,1,1,1,3,9,33}; prefix sums:
__constant__ int d_KCOFF[NEXP + 1] = {0, 1, 2, 3, 4, 7, 16, 49};

__device__ __forceinline__ float lrelu(float x) { return x > 0.f ? x : 0.2f * x; }

// ---------------- bucket samples by expert ----------------
__global__ __launch_bounds__(1024) void bucket_kernel(
    const int* __restrict__ orders, int* __restrict__ counts,
    int* __restrict__ bases, int* __restrict__ list) {
  __shared__ int c[NEXP], p[NEXP];
  int t = threadIdx.x;
  if (t < NEXP) c[t] = 0;
  __syncthreads();
  int o = orders[t];
  atomicAdd(&c[o], 1);
  __syncthreads();
  if (t == 0) {
    int s = 0;
    for (int i = 0; i < NEXP; ++i) { p[i] = s; s += c[i]; }
  }
  __syncthreads();
  if (t < NEXP) { counts[t] = c[t]; bases[t] = p[t]; }
  __syncthreads();
  int pos = atomicAdd(&p[o], 1);
  list[pos] = t;
}

// ---------------- per-expert embed+bias init vector (7 x 1024) ----------------
__global__ __launch_bounds__(1024) void hinit_kernel(
    const float* __restrict__ embed, const float* __restrict__ W_in,
    const float* __restrict__ b_in, float* __restrict__ hinit) {
  int o = blockIdx.x, j = threadIdx.x;
  float a = b_in[o * FOURH + j];
  const float* wr = W_in + (size_t)o * D_IN * FOURH + (size_t)S_MAX * FOURH + j;
#pragma unroll
  for (int e = 0; e < EMBED_DIM; ++e)
    a = fmaf(embed[o * EMBED_DIM + e], wr[(size_t)e * FOURH], a);
  hinit[o * FOURH + j] = a;
}

// ---------------- grouped layer-in GEMM, LDS-staged maze tile ----------------
// block: 256 threads; thread owns 2 consecutive j cols; MT=32 samples.
__global__ __launch_bounds__(256) void layerin_kernel(
    const float* __restrict__ mazes, const float* __restrict__ W_in,
    const int* __restrict__ counts, const int* __restrict__ bases,
    const int* __restrict__ list, const float* __restrict__ hinit,
    float* __restrict__ h) {
  int bx = blockIdx.x;
  int o = 0;
#pragma unroll
  for (int t = 1; t < NEXP; ++t)
    if (bx >= d_KCOFF[t]) o = t;
  int kc = bx - d_KCOFF[o];
  int jt = blockIdx.y, mt = blockIdx.z;
  int n = counts[o];
  int m0 = mt * MT;
  if (m0 >= n) return;

  __shared__ float smaze[MT][KT];
  __shared__ int sid[MT];
  int tid = threadIdx.x;
  if (tid < MT) {
    int r = m0 + tid;
    sid[tid] = list[bases[o] + (r < n ? r : n - 1)];
  }
  __syncthreads();

  int so = d_SIZES[o];
  int klo = kc * KCHUNK;
  int khi = min(so, klo + KCHUNK);

  int j0 = jt * 512 + tid * 2;
  const float* Wp = W_in + (size_t)o * D_IN * FOURH + j0;

  float2 acc[MT];
#pragma unroll
  for (int i = 0; i < MT; ++i) acc[i] = make_float2(0.f, 0.f);

  int row = tid >> 3, u = tid & 7;
  const float* rp = mazes + (size_t)sid[row] * S_MAX;

  for (int kb0 = klo; kb0 < khi; kb0 += KT) {
    int len = min(khi - kb0, KT);
    __syncthreads();  // smaze reuse guard
    if (len == KT) {
#pragma unroll
      for (int c = 0; c < 4; ++c) {
        int kl = c * 32 + u * 4;
        *(float4*)&smaze[row][kl] = *(const float4*)(rp + kb0 + kl);
      }
    } else {
#pragma unroll
      for (int c = 0; c < 4; ++c) {
        int kl = c * 32 + u * 4;
#pragma unroll
        for (int e = 0; e < 4; ++e) {
          int k = kb0 + kl + e;
          smaze[row][kl + e] = (k < khi) ? rp[k] : 0.f;
        }
      }
    }
    __syncthreads();
    int nq = (len + 3) >> 2;  // may read W rows up to khi+3 <= s+3 < D_IN: safe
    const float* wb = Wp + (size_t)kb0 * FOURH;
#pragma unroll 2
    for (int q = 0; q < nq; ++q) {
      float2 w0 = *(const float2*)(wb + (size_t)(q * 4 + 0) * FOURH);
      float2 w1 = *(const float2*)(wb + (size_t)(q * 4 + 1) * FOURH);
      float2 w2 = *(const float2*)(wb + (size_t)(q * 4 + 2) * FOURH);
      float2 w3 = *(const float2*)(wb + (size_t)(q * 4 + 3) * FOURH);
#pragma unroll
      for (int i = 0; i < MT; ++i) {
        float4 m = *(const float4*)&smaze[i][q * 4];  // broadcast, conflict-free
        acc[i].x = fmaf(m.x, w0.x, acc[i].x);
        acc[i].y = fmaf(m.x, w0.y, acc[i].y);
        acc[i].x = fmaf(m.y, w1.x, acc[i].x);
        acc[i].y = fmaf(m.y, w1.y, acc[i].y);
        acc[i].x = fmaf(m.z, w2.x, acc[i].x);
        acc[i].y = fmaf(m.z, w2.y, acc[i].y);
        acc[i].x = fmaf(m.w, w3.x, acc[i].x);
        acc[i].y = fmaf(m.w, w3.y, acc[i].y);
      }
    }
  }

  float2 hv = make_float2(0.f, 0.f);
  if (kc == 0) {
    hv.x = hinit[o * FOURH + j0];
    hv.y = hinit[o * FOURH + j0 + 1];
  }
  bool single = (d_KCOFF[o + 1] - d_KCOFF[o]) == 1;
  int lim = n - m0;
#pragma unroll
  for (int i = 0; i < MT; ++i) {
    if (i < lim) {
      float* hp = &h[(size_t)sid[i] * FOURH + j0];
      if (single) {
        hp[0] = acc[i].x + hv.x;
        hp[1] = acc[i].y + hv.y;
      } else {
        atomicAdd(hp, acc[i].x + hv.x);
        atomicAdd(hp + 1, acc[i].y + hv.y);
      }
    }
  }
}

// ---------------- dense MLP layer, LDS-staged A tile, fused activations ------
template <int KD, int JD, bool ACT_IN>
__global__ __launch_bounds__(256) void mlp_kernel(
    const float* __restrict__ X, const float* __restrict__ W,
    const float* __restrict__ b, float* __restrict__ Y) {
  constexpr int MT2 = 8, KT2 = 256;
  __shared__ float sh[MT2][KT2];
  int tid = threadIdx.x;
  int j = blockIdx.x * 256 + tid;
  int m0 = blockIdx.y * MT2;
  int row = tid >> 5, u = tid & 31;
  const float* xp = X + (size_t)(m0 + row) * KD;
  float acc[MT2];
#pragma unroll
  for (int i = 0; i < MT2; ++i) acc[i] = 0.f;
  for (int kb0 = 0; kb0 < KD; kb0 += KT2) {
    __syncthreads();
#pragma unroll
    for (int c = 0; c < 2; ++c) {
      int kl = c * 128 + u * 4;
      float4 v = *(const float4*)(xp + kb0 + kl);
      if (ACT_IN) {
        v.x = lrelu(v.x); v.y = lrelu(v.y); v.z = lrelu(v.z); v.w = lrelu(v.w);
      }
      *(float4*)&sh[row][kl] = v;
    }
    __syncthreads();
    const float* wb = W + (size_t)kb0 * JD + j;
#pragma unroll 4
    for (int q = 0; q < KT2 / 4; ++q) {
      float w0 = wb[(size_t)(q * 4 + 0) * JD];
      float w1 = wb[(size_t)(q * 4 + 1) * JD];
      float w2 = wb[(size_t)(q * 4 + 2) * JD];
      float w3 = wb[(size_t)(q * 4 + 3) * JD];
#pragma unroll
      for (int i = 0; i < MT2; ++i) {
        float4 m = *(const float4*)&sh[i][q * 4];  // broadcast
        acc[i] = fmaf(m.x, w0, acc[i]);
        acc[i] = fmaf(m.y, w1, acc[i]);
        acc[i] = fmaf(m.z, w2, acc[i]);
        acc[i] = fmaf(m.w, w3, acc[i]);
      }
    }
  }
  float bb = b[j];
#pragma unroll
  for (int i = 0; i < MT2; ++i)
    Y[(size_t)(m0 + i) * JD + j] = lrelu(acc[i] + bb);
}

// ---------------- layer3: [1024,256] @ [256,1] + sigmoid ----------------
__global__ __launch_bounds__(256) void layer3_kernel(
    const float* __restrict__ z2, const float* __restrict__ W3,
    const float* __restrict__ b3, float* __restrict__ out) {
  int wave = threadIdx.x >> 6, lane = threadIdx.x & 63;
  int b = blockIdx.x * 4 + wave;
  float4 v = *(const float4*)&z2[(size_t)b * HID + lane * 4];
  float4 w = *(const float4*)&W3[lane * 4];
  float d = v.x * w.x + v.y * w.y + v.z * w.z + v.w * w.w;
#pragma unroll
  for (int off = 32; off; off >>= 1) d += __shfl_down(d, off);
  if (lane == 0) out[b] = 1.f / (1.f + expf(-(d + b3[0])));
}

extern "C" void kernel_launch(void* const* d_in, const int* in_sizes, int n_in,
                              void* d_out, int out_size, void* d_ws, size_t ws_size,
                              hipStream_t stream) {
  const float* mazes = (const float*)d_in[0];
  const int* orders = (const int*)d_in[1];
  const float* embed = (const float*)d_in[2];
  const float* W_in = (const float*)d_in[3];
  const float* b_in = (const float*)d_in[4];
  const float* W1 = (const float*)d_in[5];
  const float* b1 = (const float*)d_in[6];
  const float* W2 = (const float*)d_in[7];
  const float* b2 = (const float*)d_in[8];
  const float* W3 = (const float*)d_in[9];
  const float* b3 = (const float*)d_in[10];
  float* out = (float*)d_out;

  char* ws = (char*)d_ws;
  int* counts = (int*)ws;       // 7 ints
  int* bases = counts + 8;      // 7 ints
  int* list = counts + 16;      // 1024 ints
  float* hinit = (float*)(ws + 64 * 1024);                     // 7*1024 f32
  float* h = (float*)(ws + 128 * 1024);                        // 1024*1024 f32 (4 MB)
  float* z1 = (float*)(ws + 128 * 1024 + 4 * 1024 * 1024);     // 1024*512 f32 (2 MB)
  float* z2 = h;  // overlay: h is dead after layer1 consumes it

  bucket_kernel<<<1, 1024, 0, stream>>>(orders, counts, bases, list);
  hinit_kernel<<<NEXP, 1024, 0, stream>>>(embed, W_in, b_in, hinit);
  hipMemsetAsync(h, 0, (size_t)BATCH * FOURH * sizeof(float), stream);
  layerin_kernel<<<dim3(49, 2, 32), 256, 0, stream>>>(mazes, W_in, counts, bases, list, hinit, h);
  mlp_kernel<FOURH, TWOH, true><<<dim3(2, 128), 256, 0, stream>>>(h, W1, b1, z1);
  mlp_kernel<TWOH, HID, false><<<dim3(1, 128), 256, 0, stream>>>(z1, W2, b2, z2);
  layer3_kernel<<<256, 256, 0, stream>>>(z2, W3, b3, out);
}

// Round 3
// 807.785 us; speedup vs baseline: 1.5717x; 1.1566x over previous
//
#include <hip/hip_runtime.h>
#include <cstdint>
#include <cstddef>

#define NEXP 7
#define EMBED_DIM 16
#define FOURH 1024
#define TWOH 512
#define HID 256
#define S_MAX 16641
#define D_IN (S_MAX + EMBED_DIM)
#define BATCH 1024
#define MTILE 192
#define MROWS 384  // 2 m-tiles of insurance capacity per expert

__constant__ int d_SIZES[NEXP] = {9, 25, 81, 289, 1089, 4225, 16641};
__constant__ int d_KPAD[NEXP] = {64, 64, 128, 320, 1152, 4288, 16704};
__constant__ int d_AOFF[NEXP] = {0, 64, 128, 256, 576, 1728, 6016};  // cum KPAD
// ceil(KPAD/512) = {1,1,1,1,3,9,33}; prefix:
__constant__ int d_KCOFF[NEXP + 1] = {0, 1, 2, 3, 4, 7, 16, 49};

typedef short bf16x8 __attribute__((ext_vector_type(8)));
typedef float f32x4 __attribute__((ext_vector_type(4)));

__device__ __forceinline__ float lrelu(float x) { return x > 0.f ? x : 0.2f * x; }

__device__ __forceinline__ unsigned short f2bf(float x) {
  union { float f; unsigned u; } v;
  v.f = x;
  unsigned r = v.u + 0x7FFFu + ((v.u >> 16) & 1u);  // RNE
  return (unsigned short)(r >> 16);
}

// ---------------- bucket samples by expert ----------------
__global__ __launch_bounds__(1024) void bucket_kernel(
    const int* __restrict__ orders, int* __restrict__ counts,
    int* __restrict__ bases, int* __restrict__ list) {
  __shared__ int c[NEXP], p[NEXP];
  int t = threadIdx.x;
  if (t < NEXP) c[t] = 0;
  __syncthreads();
  int o = orders[t];
  atomicAdd(&c[o], 1);
  __syncthreads();
  if (t == 0) {
    int s = 0;
    for (int i = 0; i < NEXP; ++i) { p[i] = s; s += c[i]; }
  }
  __syncthreads();
  if (t < NEXP) { counts[t] = c[t]; bases[t] = p[t]; }
  __syncthreads();
  int pos = atomicAdd(&p[o], 1);
  list[pos] = t;
}

// ---------------- per-expert embed+bias init vector (7 x 1024) ----------------
__global__ __launch_bounds__(1024) void hinit_kernel(
    const float* __restrict__ embed, const float* __restrict__ W_in,
    const float* __restrict__ b_in, float* __restrict__ hinit) {
  int o = blockIdx.x, j = threadIdx.x;
  float a = b_in[o * FOURH + j];
  const float* wr = W_in + (size_t)o * D_IN * FOURH + (size_t)S_MAX * FOURH + j;
#pragma unroll
  for (int e = 0; e < EMBED_DIM; ++e)
    a = fmaf(embed[o * EMBED_DIM + e], wr[(size_t)e * FOURH], a);
  hinit[o * FOURH + j] = a;
}

// ---------------- broadcast hinit into h by order ----------------
__global__ __launch_bounds__(256) void hb_kernel(
    const int* __restrict__ orders, const float* __restrict__ hinit,
    float* __restrict__ h) {
  int b = blockIdx.x;
  int o = orders[b];
  const float4* src = (const float4*)(hinit + (size_t)o * FOURH);
  float4* dst = (float4*)(h + (size_t)b * FOURH);
  dst[threadIdx.x] = src[threadIdx.x];
}

// ---------------- gather + fp32->bf16 convert mazes into bucketed padded Ab --
// Ab[o]: MROWS rows x KPAD(o) bf16, rows >= n_o and k >= s_o are zero.
__global__ __launch_bounds__(256) void gather_kernel(
    const float* __restrict__ mazes, const int* __restrict__ counts,
    const int* __restrict__ bases, const int* __restrict__ list,
    unsigned short* __restrict__ Ab) {
  int o = blockIdx.x / MROWS;
  int m = blockIdx.x % MROWS;
  int n = counts[o];
  int so = d_SIZES[o];
  int Kp = d_KPAD[o];
  const float* src = nullptr;
  if (m < n) src = mazes + (size_t)list[bases[o] + m] * S_MAX;
  unsigned short* dst = Ab + (size_t)d_AOFF[o] * MROWS + (size_t)m * Kp;
  int nk8 = Kp >> 3;
  for (int k8 = threadIdx.x; k8 < nk8; k8 += 256) {
    int k = k8 * 8;
    union { unsigned short u[8]; uint4 v; } pk;
#pragma unroll
    for (int e = 0; e < 8; ++e) {
      float val = (src && (k + e) < so) ? src[k + e] : 0.f;
      pk.u[e] = f2bf(val);
    }
    *(uint4*)(dst + k) = pk.v;
  }
}

// ---------------- layer-in grouped GEMM via bf16 MFMA ----------------
// grid: x = 49 (o,kc) chunk instances, y = 8 n-tiles of 128, z = 2 m-tiles of 192.
// block: 256 thr = 4 waves; wave w covers cols [y*128 + w*32, +32) as 2 n-subtiles.
__global__ __launch_bounds__(256, 2) void layerin_mfma(
    const unsigned short* __restrict__ Ab, const float* __restrict__ W_in,
    const int* __restrict__ counts, const int* __restrict__ bases,
    const int* __restrict__ list, float* __restrict__ h) {
  int bx = blockIdx.x;
  int o = 0;
#pragma unroll
  for (int t = 1; t < NEXP; ++t)
    if (bx >= d_KCOFF[t]) o = t;
  int kc = bx - d_KCOFF[o];
  int n = counts[o];
  int m_base = blockIdx.z * MTILE;
  if (m_base >= n) return;  // insurance tile unused almost always

  __shared__ unsigned short sA[8 * 194 * 8];  // [kg][m pad 194][8] bf16
  __shared__ int sid[MTILE];

  int tid = threadIdx.x;
  int wave = tid >> 6, lane = tid & 63;
  int q = lane >> 4, l16 = lane & 15;

  if (tid < MTILE) sid[tid] = (m_base + tid < n) ? list[bases[o] + m_base + tid] : 0;

  int so = d_SIZES[o];
  int Kp = d_KPAD[o];
  int klo = kc * 512;
  int klen = min(512, Kp - klo);  // multiple of 64

  int n0 = blockIdx.y * 128 + wave * 32;
  const float* Wc = W_in + (size_t)o * D_IN * FOURH + n0 + l16;
  const unsigned short* Abase =
      Ab + (size_t)d_AOFF[o] * MROWS + (size_t)m_base * Kp + klo;

  f32x4 acc[12][2];
#pragma unroll
  for (int mt = 0; mt < 12; ++mt) {
    acc[mt][0] = (f32x4)0.f;
    acc[mt][1] = (f32x4)0.f;
  }

  int kg = tid & 7;        // stage: k-group
  int mrow = tid >> 3;     // stage: row within round (32 rows/round)

  for (int ks = 0; ks < klen; ks += 64) {
    __syncthreads();
#pragma unroll
    for (int r = 0; r < 6; ++r) {
      int m = r * 32 + mrow;
      uint4 v = *(const uint4*)(Abase + (size_t)m * Kp + ks + kg * 8);
      *(uint4*)&sA[((kg * 194 + m) << 3)] = v;
    }
    __syncthreads();
#pragma unroll
    for (int st = 0; st < 2; ++st) {
      int kb = klo + ks + st * 32 + q * 8;
      bf16x8 bf0, bf1;
#pragma unroll
      for (int j = 0; j < 8; ++j) {
        int kj = kb + j;
        if (kj >= so) kj = so - 1;  // A is zero there; clamp keeps loads in-bounds
        float w0 = Wc[(size_t)kj * FOURH];
        float w1 = Wc[(size_t)kj * FOURH + 16];
        bf0[j] = (short)f2bf(w0);
        bf1[j] = (short)f2bf(w1);
      }
#pragma unroll
      for (int mt = 0; mt < 12; ++mt) {
        bf16x8 af = *(const bf16x8*)&sA[(((st * 4 + q) * 194 + mt * 16 + l16) << 3)];
        acc[mt][0] = __builtin_amdgcn_mfma_f32_16x16x32_bf16(af, bf0, acc[mt][0], 0, 0, 0);
        acc[mt][1] = __builtin_amdgcn_mfma_f32_16x16x32_bf16(af, bf1, acc[mt][1], 0, 0, 0);
      }
    }
  }

  int colA = n0 + l16, colB = n0 + 16 + l16;
#pragma unroll
  for (int mt = 0; mt < 12; ++mt) {
#pragma unroll
    for (int r = 0; r < 4; ++r) {
      int m = mt * 16 + q * 4 + r;
      if (m_base + m < n) {
        int s = sid[m];
        atomicAdd(&h[(size_t)s * FOURH + colA], acc[mt][0][r]);
        atomicAdd(&h[(size_t)s * FOURH + colB], acc[mt][1][r]);
      }
    }
  }
}

// ---------------- dense MLP layer, LDS-staged A tile, fused activations ------
template <int KD, int JD, bool ACT_IN>
__global__ __launch_bounds__(256) void mlp_kernel(
    const float* __restrict__ X, const float* __restrict__ W,
    const float* __restrict__ b, float* __restrict__ Y) {
  constexpr int MT2 = 8, KT2 = 256;
  __shared__ float sh[MT2][KT2];
  int tid = threadIdx.x;
  int j = blockIdx.x * 256 + tid;
  int m0 = blockIdx.y * MT2;
  int row = tid >> 5, u = tid & 31;
  const float* xp = X + (size_t)(m0 + row) * KD;
  float acc[MT2];
#pragma unroll
  for (int i = 0; i < MT2; ++i) acc[i] = 0.f;
  for (int kb0 = 0; kb0 < KD; kb0 += KT2) {
    __syncthreads();
#pragma unroll
    for (int c = 0; c < 2; ++c) {
      int kl = c * 128 + u * 4;
      float4 v = *(const float4*)(xp + kb0 + kl);
      if (ACT_IN) {
        v.x = lrelu(v.x); v.y = lrelu(v.y); v.z = lrelu(v.z); v.w = lrelu(v.w);
      }
      *(float4*)&sh[row][kl] = v;
    }
    __syncthreads();
    const float* wb = W + (size_t)kb0 * JD + j;
#pragma unroll 4
    for (int qq = 0; qq < KT2 / 4; ++qq) {
      float w0 = wb[(size_t)(qq * 4 + 0) * JD];
      float w1 = wb[(size_t)(qq * 4 + 1) * JD];
      float w2 = wb[(size_t)(qq * 4 + 2) * JD];
      float w3 = wb[(size_t)(qq * 4 + 3) * JD];
#pragma unroll
      for (int i = 0; i < MT2; ++i) {
        float4 m = *(const float4*)&sh[i][qq * 4];  // broadcast
        acc[i] = fmaf(m.x, w0, acc[i]);
        acc[i] = fmaf(m.y, w1, acc[i]);
        acc[i] = fmaf(m.z, w2, acc[i]);
        acc[i] = fmaf(m.w, w3, acc[i]);
      }
    }
  }
  float bb = b[j];
#pragma unroll
  for (int i = 0; i < MT2; ++i)
    Y[(size_t)(m0 + i) * JD + j] = lrelu(acc[i] + bb);
}

// ---------------- layer3: [1024,256] @ [256,1] + sigmoid ----------------
__global__ __launch_bounds__(256) void layer3_kernel(
    const float* __restrict__ z2, const float* __restrict__ W3,
    const float* __restrict__ b3, float* __restrict__ out) {
  int wave = threadIdx.x >> 6, lane = threadIdx.x & 63;
  int b = blockIdx.x * 4 + wave;
  float4 v = *(const float4*)&z2[(size_t)b * HID + lane * 4];
  float4 w = *(const float4*)&W3[lane * 4];
  float d = v.x * w.x + v.y * w.y + v.z * w.z + v.w * w.w;
#pragma unroll
  for (int off = 32; off; off >>= 1) d += __shfl_down(d, off);
  if (lane == 0) out[b] = 1.f / (1.f + expf(-(d + b3[0])));
}

extern "C" void kernel_launch(void* const* d_in, const int* in_sizes, int n_in,
                              void* d_out, int out_size, void* d_ws, size_t ws_size,
                              hipStream_t stream) {
  const float* mazes = (const float*)d_in[0];
  const int* orders = (const int*)d_in[1];
  const float* embed = (const float*)d_in[2];
  const float* W_in = (const float*)d_in[3];
  const float* b_in = (const float*)d_in[4];
  const float* W1 = (const float*)d_in[5];
  const float* b1 = (const float*)d_in[6];
  const float* W2 = (const float*)d_in[7];
  const float* b2 = (const float*)d_in[8];
  const float* W3 = (const float*)d_in[9];
  const float* b3 = (const float*)d_in[10];
  float* out = (float*)d_out;

  char* ws = (char*)d_ws;
  int* counts = (int*)ws;       // 7 ints
  int* bases = counts + 8;      // 7 ints
  int* list = counts + 16;      // 1024 ints
  float* hinit = (float*)(ws + 64 * 1024);                     // 7*1024 f32
  float* h = (float*)(ws + 128 * 1024);                        // 1024*1024 f32 (4 MB)
  float* z1 = (float*)(ws + 128 * 1024 + 4 * 1024 * 1024);     // 1024*512 f32 (2 MB)
  unsigned short* Ab = (unsigned short*)(ws + 128 * 1024 + 8 * 1024 * 1024);  // 17.5 MB
  float* z2 = h;  // overlay: h is dead after mlp1 consumes it

  bucket_kernel<<<1, 1024, 0, stream>>>(orders, counts, bases, list);
  hinit_kernel<<<NEXP, 1024, 0, stream>>>(embed, W_in, b_in, hinit);
  gather_kernel<<<NEXP * MROWS, 256, 0, stream>>>(mazes, counts, bases, list, Ab);
  hb_kernel<<<BATCH, 256, 0, stream>>>(orders, hinit, h);
  layerin_mfma<<<dim3(49, 8, 2), 256, 0, stream>>>(Ab, W_in, counts, bases, list, h);
  mlp_kernel<FOURH, TWOH, true><<<dim3(2, 128), 256, 0, stream>>>(h, W1, b1, z1);
  mlp_kernel<TWOH, HID, false><<<dim3(1, 128), 256, 0, stream>>>(z1, W2, b2, z2);
  layer3_kernel<<<256, 256, 0, stream>>>(z2, W3, b3, out);
}